// Round 6
// baseline (32.119 us; speedup 1.0000x reference)
//
#include <hip/hip_runtime.h>

// SoftTimeAttention: out[b,q,:] = sum_j softmax_j(-(T*(t_q-t_j))^2) * h[b,j,:]
// B=4, T=4096, H=256, f32. With ts = 4096*t, w = exp(-(ts_q-ts_j)^2) == 0
// exactly in f32 whenever |dts| > 12 (exp(-144) underflows); bucket width = 4
// scaled units => keys at bucket distance >= 4 contribute exactly 0.
//
// Structure: (1) memsetAsync zeroes per-bucket counters; (2) bucket-build
// kernel: fully parallel scatter of {ts, idx} into per-bucket lists via one
// global atomicAdd per element; (3) main kernel: each block owns QB=4 buckets,
// stages its 10-bucket window (lists are bucket-ordered) into LDS, each wave
// processes a contiguous query chunk against a +-3-bucket restricted window
// with ballot-compacted quad-row weighted accumulation.

constexpr int Bb  = 4;
constexpr int Tt  = 4096;
constexpr int Hh  = 256;
constexpr int NBK = 1024;          // buckets per batch (width 4 in ts units)
constexpr int CAP = 32;            // per-bucket capacity (Poisson(4): P(>=32)~1e-18)
constexpr int QB  = 4;             // buckets owned per main-kernel block
constexpr int WB  = QB + 6;        // staged window buckets
constexpr int WCAP = WB * CAP;     // 320 staged-candidate slots

// ws layout: cnt (Bb*NBK int) | ovf (1 int + pad) | lists (Bb*NBK*CAP uint2)
constexpr size_t CNT_BYTES  = (size_t)Bb * NBK * 4;          // 16384
constexpr size_t LISTS_OFF  = CNT_BYTES + 64;                // 8B-aligned
constexpr size_t WS_NEED    = LISTS_OFF + (size_t)Bb * NBK * CAP * 8;

__device__ __forceinline__ int bucket_of(float ts) {
    int kk = (int)(ts * 0.25f);
    return kk < 0 ? 0 : (kk > NBK - 1 ? NBK - 1 : kk);
}

// ---------------------------------------------------------------------------
// Bucket build: one element per thread, global atomic rank, direct list write.
__global__ __launch_bounds__(256) void bucket_build(
    const float* __restrict__ tvals,
    int* __restrict__ cnt, int* __restrict__ ovf,
    uint2* __restrict__ lists)
{
    const int gid = blockIdx.x * 256 + threadIdx.x;   // 0..Bb*Tt-1
    const int b = gid >> 12;
    const int j = gid & (Tt - 1);
    const float ts = tvals[(size_t)b * Tt + j] * 4096.0f;
    const int k = bucket_of(ts);
    const int pos = atomicAdd(&cnt[b * NBK + k], 1);
    if (pos < CAP) {
        uint2 pr; pr.x = __float_as_uint(ts); pr.y = (unsigned)j;
        lists[((size_t)(b * NBK + k)) * CAP + pos] = pr;
    } else {
        atomicOr(ovf, 1);
    }
}

// ---------------------------------------------------------------------------
// Accumulate <=NQ queries against staged candidates [lo,hi) in LDS.
template<int NQ>
__device__ __forceinline__ void process_pass(
    const float* __restrict__ tsL, const unsigned short* __restrict__ idL,
    int lo, int hi,
    const float* tq, const int* qi, int got, int lane,
    const float* __restrict__ hb, float* __restrict__ outb)
{
    float4 acc[NQ];
    float  den[NQ];
    #pragma unroll
    for (int g = 0; g < NQ; ++g) { acc[g] = make_float4(0.f,0.f,0.f,0.f); den[g] = 0.f; }

    for (int base = lo; base < hi; base += 64) {
        const int p = base + lane;
        const bool v = p < hi;
        const float tj = v ? tsL[p] : 3.0e18f;   // sentinel -> w == 0 exactly
        const int   jj = v ? (int)idL[p] : 0;

        float w[NQ]; float wmax = 0.f;
        #pragma unroll
        for (int g = 0; g < NQ; ++g) {
            const float x = tq[g] - tj;
            w[g] = __expf(-x * x);
            den[g] += w[g];
            wmax = fmaxf(wmax, w[g]);
        }

        unsigned long long mask = __ballot(wmax > 0.0f);
        while (mask) {
            const int s0 = __builtin_ctzll(mask); mask &= mask - 1;
            const bool h1 = mask != 0;
            const int s1 = h1 ? __builtin_ctzll(mask) : s0; if (h1) mask &= mask - 1;
            const bool h2 = mask != 0;
            const int s2 = h2 ? __builtin_ctzll(mask) : s0; if (h2) mask &= mask - 1;
            const bool h3 = mask != 0;
            const int s3 = h3 ? __builtin_ctzll(mask) : s0; if (h3) mask &= mask - 1;

            const int j0 = __shfl(jj, s0);
            const int j1 = __shfl(jj, s1);
            const int j2 = __shfl(jj, s2);
            const int j3 = __shfl(jj, s3);
            float4 h0  = *(const float4*)&hb[(size_t)j0 * Hh + lane * 4];
            float4 h1v = *(const float4*)&hb[(size_t)j1 * Hh + lane * 4];
            float4 h2v = *(const float4*)&hb[(size_t)j2 * Hh + lane * 4];
            float4 h3v = *(const float4*)&hb[(size_t)j3 * Hh + lane * 4];
            if (!h1) h1v = make_float4(0.f,0.f,0.f,0.f);
            if (!h2) h2v = make_float4(0.f,0.f,0.f,0.f);
            if (!h3) h3v = make_float4(0.f,0.f,0.f,0.f);

            #pragma unroll
            for (int g = 0; g < NQ; ++g) {
                const float a0 = __shfl(w[g], s0);
                const float a1 = __shfl(w[g], s1);
                const float a2 = __shfl(w[g], s2);
                const float a3 = __shfl(w[g], s3);
                acc[g].x += a0 * h0.x + a1 * h1v.x + a2 * h2v.x + a3 * h3v.x;
                acc[g].y += a0 * h0.y + a1 * h1v.y + a2 * h2v.y + a3 * h3v.y;
                acc[g].z += a0 * h0.z + a1 * h1v.z + a2 * h2v.z + a3 * h3v.z;
                acc[g].w += a0 * h0.w + a1 * h1v.w + a2 * h2v.w + a3 * h3v.w;
            }
        }
    }

    #pragma unroll
    for (int g = 0; g < NQ; ++g) {
        float d = den[g];
        #pragma unroll
        for (int s = 1; s < 64; s <<= 1) d += __shfl_xor(d, s);
        den[g] = d;
    }

    #pragma unroll
    for (int g = 0; g < NQ; ++g) {       // constant-index unroll (rule #20)
        if (g < got) {
            const float inv = 1.0f / den[g];
            float* orow = outb + (size_t)qi[g] * Hh + lane * 4;
            float4 o;
            o.x = acc[g].x * inv; o.y = acc[g].y * inv;
            o.z = acc[g].z * inv; o.w = acc[g].w * inv;
            *(float4*)orow = o;
        }
    }
}

// ---------------------------------------------------------------------------
__global__ __launch_bounds__(256) void stattn_main(
    const float* __restrict__ h_seq,
    const float* __restrict__ tvals,
    const int* __restrict__ cnt, const int* __restrict__ ovf,
    const uint2* __restrict__ lists,
    float* __restrict__ out)
{
    __shared__ float tsL[WCAP];
    __shared__ unsigned short idL[WCAP];
    __shared__ int bcnt[WB];
    __shared__ int boff[WB + 1];

    const int tid  = threadIdx.x;
    const int lane = tid & 63;
    const int wv   = tid >> 6;

    // XCD-contiguous swizzle: 1024 blocks -> 128 contiguous logical per XCD.
    const int phys = blockIdx.x;
    const int lb   = (phys & 7) * 128 + (phys >> 3);
    const int b    = lb >> 8;
    const int m    = lb & 255;
    const int k0   = m * QB;

    const float* hb   = h_seq + (size_t)b * Tt * Hh;
    float*       outb = out   + (size_t)b * Tt * Hh;

    // ---- window bucket counts + prefix (wave 0, shfl scan over 16 lanes)
    if (tid < 64) {
        int c = 0;
        if (lane < WB) {
            const int w = k0 - 3 + lane;
            if (w >= 0 && w < NBK) {
                c = cnt[b * NBK + w];
                c = c > CAP ? CAP : c;
            }
            bcnt[lane] = c;
        }
        int x = c;
        #pragma unroll
        for (int d = 1; d < 16; d <<= 1) {
            const int y = __shfl_up(x, d);
            if (lane >= d) x += y;
        }
        if (lane < WB) boff[lane] = x - c;
        if (lane == WB - 1) boff[WB] = x;
    }
    __syncthreads();

    // ---- gather window lists into LDS (bucket-ordered)
    for (int i = tid; i < WCAP; i += 256) {
        const int wb = i >> 5;          // CAP = 32
        const int e  = i & (CAP - 1);
        if (e < bcnt[wb]) {
            const uint2 pr = lists[((size_t)(b * NBK + (k0 - 3 + wb))) * CAP + e];
            const int slot = boff[wb] + e;
            tsL[slot] = __uint_as_float(pr.x);
            idL[slot] = (unsigned short)pr.y;
        }
    }
    __syncthreads();

    if (*ovf) {
        // exact dense fallback (never triggers for this input): each wave
        // handles its share of this block's own-bucket queries densely.
        const float* tb = tvals + (size_t)b * Tt;
        for (int j = wv; j < Tt; j += 4) {
            const float tsq = tb[j] * 4096.0f;
            const int   kk  = bucket_of(tsq);
            if (kk < k0 || kk >= k0 + QB) continue;
            float4 acc = make_float4(0.f,0.f,0.f,0.f);
            float  den = 0.f;
            for (int key = 0; key < Tt; ++key) {
                const float x = tsq - tb[key] * 4096.0f;
                const float w = __expf(-x * x);
                den += w;
                if (w > 0.f) {
                    const float4 hv = *(const float4*)&hb[(size_t)key * Hh + lane * 4];
                    acc.x += w * hv.x; acc.y += w * hv.y;
                    acc.z += w * hv.z; acc.w += w * hv.w;
                }
            }
            const float inv = 1.0f / den;
            float4 o;
            o.x = acc.x * inv; o.y = acc.y * inv;
            o.z = acc.z * inv; o.w = acc.w * inv;
            *(float4*)&outb[(size_t)j * Hh + lane * 4] = o;
        }
        return;
    }

    // ---- own queries = staged slots of buckets [3, 3+QB) (contiguous)
    const int own_lo = boff[3];
    const int own_hi = boff[3 + QB];
    const int nq = own_hi - own_lo;
    if (nq <= 0) return;

    const int chunk = (nq + 3) >> 2;            // contiguous chunk per wave
    const int qs0 = own_lo + wv * chunk;
    int qe = qs0 + chunk; qe = qe > own_hi ? own_hi : qe;

    for (int qs = qs0; qs < qe; qs += 8) {
        int got = qe - qs; got = got > 8 ? 8 : got;

        float tq[8]; int qi[8];
        #pragma unroll
        for (int g = 0; g < 8; ++g) {
            if (g < got) { tq[g] = tsL[qs + g]; qi[g] = (int)idL[qs + g]; }
            else         { tq[g] = -3.0e18f;    qi[g] = 0; }
        }

        // restricted candidate window: queries are bucket-monotone in staged
        // order, so [bucket(first)-3, bucket(last)+3] covers all nonzero w.
        const int bminq = bucket_of(tq[0]);
        const int bmaxq = bucket_of(tsL[qs + got - 1]);   // LDS, runtime idx ok
        int wlo = bminq - k0;            // = (bminq-3) - (k0-3)
        int whi = bmaxq - k0 + 7;        // exclusive
        wlo = wlo < 0 ? 0 : wlo;
        whi = whi > WB ? WB : whi;
        const int lo = boff[wlo];
        const int hi = boff[whi];

        if (got <= 4) process_pass<4>(tsL, idL, lo, hi, tq, qi, got, lane, hb, outb);
        else          process_pass<8>(tsL, idL, lo, hi, tq, qi, got, lane, hb, outb);
    }
}

// ---------------------------------------------------------------------------
// Naive dense fallback if ws is too small (never expected; kept for safety).
__global__ __launch_bounds__(64) void stattn_naive(
    const float* __restrict__ h_seq,
    const float* __restrict__ tvals,
    float* __restrict__ out)
{
    const int gid  = blockIdx.x;        // b*Tt + q
    const int b    = gid >> 12;
    const int q    = gid & (Tt - 1);
    const int lane = threadIdx.x;
    const float* tb = tvals + (size_t)b * Tt;
    const float* hb = h_seq + (size_t)b * Tt * Hh;
    const float tsq = tb[q] * 4096.0f;
    float4 acc = make_float4(0.f,0.f,0.f,0.f);
    float den = 0.f;
    for (int j = 0; j < Tt; ++j) {
        const float x = tsq - tb[j] * 4096.0f;
        const float w = __expf(-x * x);
        den += w;
        if (w > 0.f) {
            const float4 hv = *(const float4*)&hb[(size_t)j * Hh + lane * 4];
            acc.x += w * hv.x; acc.y += w * hv.y;
            acc.z += w * hv.z; acc.w += w * hv.w;
        }
    }
    const float inv = 1.0f / den;
    float4 o;
    o.x = acc.x * inv; o.y = acc.y * inv; o.z = acc.z * inv; o.w = acc.w * inv;
    *(float4*)&out[((size_t)b * Tt + q) * Hh + lane * 4] = o;
}

extern "C" void kernel_launch(void* const* d_in, const int* in_sizes, int n_in,
                              void* d_out, int out_size, void* d_ws, size_t ws_size,
                              hipStream_t stream) {
    const float* h_seq = (const float*)d_in[0];
    const float* tvals = (const float*)d_in[1];
    float* out = (float*)d_out;

    if (ws_size >= WS_NEED) {
        int*   cnt   = (int*)d_ws;
        int*   ovf   = (int*)((char*)d_ws + CNT_BYTES);
        uint2* lists = (uint2*)((char*)d_ws + LISTS_OFF);
        hipMemsetAsync(d_ws, 0, CNT_BYTES + 64, stream);   // cnt + ovf
        bucket_build<<<dim3(Bb * Tt / 256), dim3(256), 0, stream>>>(
            tvals, cnt, ovf, lists);
        stattn_main<<<dim3(Bb * (NBK / QB)), dim3(256), 0, stream>>>(
            h_seq, tvals, cnt, ovf, lists, out);
    } else {
        stattn_naive<<<dim3(Bb * Tt), dim3(64), 0, stream>>>(h_seq, tvals, out);
    }
}

// Round 7
// 29.076 us; speedup vs baseline: 1.1047x; 1.1047x over previous
//
#include <hip/hip_runtime.h>

// SoftTimeAttention: out[b,q,:] = sum_j softmax_j(-(T*(t_q-t_j))^2) * h[b,j,:]
// B=4, T=4096, H=256, f32. With ts = 4096*t, w = exp(-(ts_q-ts_j)^2) == 0
// exactly in f32 whenever |dts| > 12; bucket width = 4 scaled units, so keys
// beyond +-3 buckets contribute exactly 0 (exp(-144) underflows even in the
// f32 reference). Single fused kernel:
//   phase 1: block scans batch t (16 KB, L2), stages its 10-bucket window
//            (E~40 cands) into LDS via wave-ballot compaction (no serial
//            chains, ~1 LDS atomic per wave-round).
//   phase 2: each wave extracts its own bucket's queries with parallel
//            ballot-rank rounds (replaces R5's serial cursor walk).
//   phase 3: ballot-compacted quad-row weighted accumulation (R4-proven).
// No workspace, no sort, one dispatch. Overflow => exact dense fallback.

constexpr int Bb   = 4;
constexpr int Tt   = 4096;
constexpr int Hh   = 256;
constexpr int NBK  = 1024;    // buckets per batch (width 4 in ts units)
constexpr int QB   = 4;       // buckets owned per block (1 per wave)
constexpr int CAP  = 192;     // staged-candidate cap (E~40, Poisson tail ~0)
constexpr int QCAP = 24;      // per-wave query cap  (E~4)

__device__ __forceinline__ int bucket_of(float ts) {
    int kk = (int)(ts * 0.25f);
    return kk < 0 ? 0 : (kk > NBK - 1 ? NBK - 1 : kk);
}

// Accumulate <=NQ queries against staged candidates [0,nc) in LDS.
template<int NQ>
__device__ __forceinline__ void process_pass(
    const float* __restrict__ tsL, const unsigned short* __restrict__ idL,
    int nc, const float* tq, const int* qi, int got, int lane,
    const float* __restrict__ hb, float* __restrict__ outb)
{
    float4 acc[NQ];
    float  den[NQ];
    #pragma unroll
    for (int g = 0; g < NQ; ++g) { acc[g] = make_float4(0.f,0.f,0.f,0.f); den[g] = 0.f; }

    for (int base = 0; base < nc; base += 64) {
        const int p = base + lane;
        const bool v = p < nc;
        const float tj = v ? tsL[p] : 3.0e18f;   // sentinel -> w == 0 exactly
        const int   jj = v ? (int)idL[p] : 0;

        float w[NQ]; float wmax = 0.f;
        #pragma unroll
        for (int g = 0; g < NQ; ++g) {
            const float x = tq[g] - tj;
            w[g] = __expf(-x * x);
            den[g] += w[g];
            wmax = fmaxf(wmax, w[g]);
        }

        unsigned long long mask = __ballot(wmax > 0.0f);
        while (mask) {
            const int s0 = __builtin_ctzll(mask); mask &= mask - 1;
            const bool h1 = mask != 0;
            const int s1 = h1 ? __builtin_ctzll(mask) : s0; if (h1) mask &= mask - 1;
            const bool h2 = mask != 0;
            const int s2 = h2 ? __builtin_ctzll(mask) : s0; if (h2) mask &= mask - 1;
            const bool h3 = mask != 0;
            const int s3 = h3 ? __builtin_ctzll(mask) : s0; if (h3) mask &= mask - 1;

            const int j0 = __shfl(jj, s0);
            const int j1 = __shfl(jj, s1);
            const int j2 = __shfl(jj, s2);
            const int j3 = __shfl(jj, s3);
            float4 h0  = *(const float4*)&hb[(size_t)j0 * Hh + lane * 4];
            float4 h1v = *(const float4*)&hb[(size_t)j1 * Hh + lane * 4];
            float4 h2v = *(const float4*)&hb[(size_t)j2 * Hh + lane * 4];
            float4 h3v = *(const float4*)&hb[(size_t)j3 * Hh + lane * 4];
            if (!h1) h1v = make_float4(0.f,0.f,0.f,0.f);
            if (!h2) h2v = make_float4(0.f,0.f,0.f,0.f);
            if (!h3) h3v = make_float4(0.f,0.f,0.f,0.f);

            #pragma unroll
            for (int g = 0; g < NQ; ++g) {
                const float a0 = __shfl(w[g], s0);
                const float a1 = __shfl(w[g], s1);
                const float a2 = __shfl(w[g], s2);
                const float a3 = __shfl(w[g], s3);
                acc[g].x += a0 * h0.x + a1 * h1v.x + a2 * h2v.x + a3 * h3v.x;
                acc[g].y += a0 * h0.y + a1 * h1v.y + a2 * h2v.y + a3 * h3v.y;
                acc[g].z += a0 * h0.z + a1 * h1v.z + a2 * h2v.z + a3 * h3v.z;
                acc[g].w += a0 * h0.w + a1 * h1v.w + a2 * h2v.w + a3 * h3v.w;
            }
        }
    }

    #pragma unroll
    for (int g = 0; g < NQ; ++g) {
        float d = den[g];
        #pragma unroll
        for (int s = 1; s < 64; s <<= 1) d += __shfl_xor(d, s);
        den[g] = d;
    }

    #pragma unroll
    for (int g = 0; g < NQ; ++g) {       // constant-index unroll (rule #20)
        if (g < got) {
            const float inv = 1.0f / den[g];
            float* orow = outb + (size_t)qi[g] * Hh + lane * 4;
            float4 o;
            o.x = acc[g].x * inv; o.y = acc[g].y * inv;
            o.z = acc[g].z * inv; o.w = acc[g].w * inv;
            *(float4*)orow = o;
        }
    }
}

__global__ __launch_bounds__(256) void stattn_fused(
    const float* __restrict__ h_seq,
    const float* __restrict__ tvals,
    float* __restrict__ out)
{
    __shared__ float tsL[CAP];
    __shared__ unsigned short idL[CAP];
    __shared__ float qtsS[QB][QCAP];
    __shared__ unsigned short qidS[QB][QCAP];
    __shared__ int nc_s, ovf_s;

    const int tid  = threadIdx.x;
    const int lane = tid & 63;
    const int wv   = tid >> 6;

    // XCD-contiguous swizzle: 1024 blocks -> 128 contiguous logical per XCD,
    // 2 XCDs per batch so t (16 KB) and the 4 MB h panel stay L2-resident.
    const int phys = blockIdx.x;
    const int lb   = (phys & 7) * 128 + (phys >> 3);
    const int b    = lb >> 8;
    const int m    = lb & 255;
    const int k0   = m * QB;

    const float* tb   = tvals + (size_t)b * Tt;
    const float* hb   = h_seq + (size_t)b * Tt * Hh;
    float*       outb = out   + (size_t)b * Tt * Hh;

    if (tid == 0) { nc_s = 0; ovf_s = 0; }
    __syncthreads();

    // ---- phase 1: scan batch t, ballot-compact window cands into LDS
    const unsigned long long lmask = (1ull << lane) - 1ull;
    #pragma unroll
    for (int c = 0; c < 4; ++c) {
        const int j4 = c * 1024 + tid * 4;
        const float4 tv = *(const float4*)&tb[j4];
        #pragma unroll
        for (int u = 0; u < 4; ++u) {
            const float ts = (&tv.x)[u] * 4096.0f;
            const int   kk = bucket_of(ts);
            const bool pred = (kk >= k0 - 3) && (kk <= k0 + QB + 2);
            const unsigned long long mask = __ballot(pred);
            if (mask) {                                 // wave-uniform branch
                const int cntm = __popcll(mask);
                int base;
                if (lane == 0) base = atomicAdd(&nc_s, cntm);
                base = __shfl(base, 0);
                if (pred) {
                    const int slot = base + __popcll(mask & lmask);
                    if (slot < CAP) {
                        tsL[slot] = ts;
                        idL[slot] = (unsigned short)(j4 + u);
                    } else ovf_s = 1;
                }
            }
        }
    }
    __syncthreads();
    const int nc = nc_s < CAP ? nc_s : CAP;

    // ---- phase 2: per-wave query extraction (parallel ballot ranks)
    const int kw = k0 + wv;
    int qb = 0;
    for (int c0 = 0; c0 < nc; c0 += 64) {
        const int p = c0 + lane;
        const bool v = p < nc;
        const float ts = v ? tsL[p] : -1.0f;
        const bool pred = v && (bucket_of(ts) == kw);
        const unsigned long long mask = __ballot(pred);
        if (pred) {
            const int r = qb + __popcll(mask & lmask);
            if (r < QCAP) { qtsS[wv][r] = ts; qidS[wv][r] = idL[p]; }
            else ovf_s = 1;
        }
        qb += __popcll(mask);
    }
    __syncthreads();    // ovf_s must be block-uniform for the fallback branch

    if (ovf_s) {
        // exact dense fallback (never triggers for U[0,1) input; keeps the
        // kernel correct for any input). Wave wv: queries j % 4 == wv.
        for (int j = wv; j < Tt; j += 4) {
            const float tsq = tb[j] * 4096.0f;
            const int   kk  = bucket_of(tsq);
            if (kk < k0 || kk >= k0 + QB) continue;
            float4 acc = make_float4(0.f,0.f,0.f,0.f);
            float  den = 0.f;
            for (int key = 0; key < Tt; ++key) {
                const float x = tsq - tb[key] * 4096.0f;
                const float w = __expf(-x * x);
                den += w;
                if (w > 0.f) {
                    const float4 hv = *(const float4*)&hb[(size_t)key * Hh + lane * 4];
                    acc.x += w * hv.x; acc.y += w * hv.y;
                    acc.z += w * hv.z; acc.w += w * hv.w;
                }
            }
            const float inv = 1.0f / den;
            float4 o;
            o.x = acc.x * inv; o.y = acc.y * inv;
            o.z = acc.z * inv; o.w = acc.w * inv;
            *(float4*)&outb[(size_t)j * Hh + lane * 4] = o;
        }
        return;
    }

    // ---- phase 3: process own-bucket queries in passes of <=8
    const int nqw = qb;                       // wave-uniform
    for (int qs = 0; qs < nqw; qs += 8) {
        const int got = (nqw - qs) > 8 ? 8 : (nqw - qs);

        float tq[8]; int qi[8];
        #pragma unroll
        for (int g = 0; g < 8; ++g) {         // constant-index reads (rule #20)
            if (g < got) { tq[g] = qtsS[wv][qs + g]; qi[g] = (int)qidS[wv][qs + g]; }
            else         { tq[g] = -3.0e18f;         qi[g] = 0; }
        }

        if (got <= 4) process_pass<4>(tsL, idL, nc, tq, qi, got, lane, hb, outb);
        else          process_pass<8>(tsL, idL, nc, tq, qi, got, lane, hb, outb);
    }
}

extern "C" void kernel_launch(void* const* d_in, const int* in_sizes, int n_in,
                              void* d_out, int out_size, void* d_ws, size_t ws_size,
                              hipStream_t stream) {
    const float* h_seq = (const float*)d_in[0];
    const float* tvals = (const float*)d_in[1];
    float* out = (float*)d_out;
    // grid = B * (NBK / QB) = 4 * 256 = 1024 blocks, 256 threads (4 waves)
    stattn_fused<<<dim3(Bb * (NBK / QB)), dim3(256), 0, stream>>>(h_seq, tvals, out);
    (void)d_ws; (void)ws_size; (void)in_sizes; (void)n_in; (void)out_size;
}

// Round 8
// 28.711 us; speedup vs baseline: 1.1187x; 1.0127x over previous
//
#include <hip/hip_runtime.h>

// SoftTimeAttention: out[b,q,:] = sum_j softmax_j(-(T*(t_q-t_j))^2) * h[b,j,:]
// B=4, T=4096, H=256, f32. With ts = 4096*t, w = exp(-(ts_q-ts_j)^2) == 0
// exactly in f32 whenever |dts| > 12 (exp(-144) underflows); bucket width = 4
// ts units, so keys beyond +-3 buckets contribute exactly 0 — the windowed
// computation is bit-identical to dense f32.
//
// Single fused kernel, no workspace. Per block (4 buckets, 1 per wave):
//   phase 1: scan batch t (16 KB, L2); in-window values go DIRECTLY to LDS
//            slot [bucket][atomicAdd] — no ballot compaction, no serial
//            chains; common path is ~8 VALU ops, branch execz-skipped.
//   phase 2: 10-lane shfl prefix over bucket counts + 2-round slot move
//            => contiguous bucket-ordered candidate list. A wave's queries
//            are exactly its own bucket's slots (no extraction pass).
//   phase 3: ballot-compacted quad-row weighted accumulation (R4-proven),
//            candidates restricted to the wave's 7-bucket sub-window.
// Overflow (impossible for this input: P(Poisson(4) >= 32) ~ 1e-17 per
// bucket) => exact dense fallback.

constexpr int Bb   = 4;
constexpr int Tt   = 4096;
constexpr int Hh   = 256;
constexpr int NBK  = 1024;     // buckets per batch (width 4 in ts units)
constexpr int QB   = 4;        // buckets owned per block (1 per wave)
constexpr int WB   = QB + 6;   // 10 staged window buckets
constexpr int CAPB = 32;       // per-bucket slot capacity
constexpr int WCAP = WB * CAPB;

__device__ __forceinline__ int bucket_of(float ts) {
    int kk = (int)(ts * 0.25f);
    return kk < 0 ? 0 : (kk > NBK - 1 ? NBK - 1 : kk);
}

// Accumulate <=NQ queries against compacted candidates [lo,hi) in LDS.
template<int NQ>
__device__ __forceinline__ void process_pass(
    const float* __restrict__ tsL, const unsigned short* __restrict__ idL,
    int lo, int hi, const float* tq, const int* qi, int got, int lane,
    const float* __restrict__ hb, float* __restrict__ outb)
{
    float4 acc[NQ];
    float  den[NQ];
    #pragma unroll
    for (int g = 0; g < NQ; ++g) { acc[g] = make_float4(0.f,0.f,0.f,0.f); den[g] = 0.f; }

    for (int base = lo; base < hi; base += 64) {
        const int p = base + lane;
        const bool v = p < hi;
        const float tj = v ? tsL[p] : 3.0e18f;   // sentinel -> w == 0 exactly
        const int   jj = v ? (int)idL[p] : 0;

        float w[NQ]; float wmax = 0.f;
        #pragma unroll
        for (int g = 0; g < NQ; ++g) {
            const float x = tq[g] - tj;
            w[g] = __expf(-x * x);
            den[g] += w[g];
            wmax = fmaxf(wmax, w[g]);
        }

        unsigned long long mask = __ballot(wmax > 0.0f);
        while (mask) {
            const int s0 = __builtin_ctzll(mask); mask &= mask - 1;
            const bool h1 = mask != 0;
            const int s1 = h1 ? __builtin_ctzll(mask) : s0; if (h1) mask &= mask - 1;
            const bool h2 = mask != 0;
            const int s2 = h2 ? __builtin_ctzll(mask) : s0; if (h2) mask &= mask - 1;
            const bool h3 = mask != 0;
            const int s3 = h3 ? __builtin_ctzll(mask) : s0; if (h3) mask &= mask - 1;

            const int j0 = __shfl(jj, s0);
            const int j1 = __shfl(jj, s1);
            const int j2 = __shfl(jj, s2);
            const int j3 = __shfl(jj, s3);
            float4 h0  = *(const float4*)&hb[(size_t)j0 * Hh + lane * 4];
            float4 h1v = *(const float4*)&hb[(size_t)j1 * Hh + lane * 4];
            float4 h2v = *(const float4*)&hb[(size_t)j2 * Hh + lane * 4];
            float4 h3v = *(const float4*)&hb[(size_t)j3 * Hh + lane * 4];
            if (!h1) h1v = make_float4(0.f,0.f,0.f,0.f);
            if (!h2) h2v = make_float4(0.f,0.f,0.f,0.f);
            if (!h3) h3v = make_float4(0.f,0.f,0.f,0.f);

            #pragma unroll
            for (int g = 0; g < NQ; ++g) {
                const float a0 = __shfl(w[g], s0);
                const float a1 = __shfl(w[g], s1);
                const float a2 = __shfl(w[g], s2);
                const float a3 = __shfl(w[g], s3);
                acc[g].x += a0 * h0.x + a1 * h1v.x + a2 * h2v.x + a3 * h3v.x;
                acc[g].y += a0 * h0.y + a1 * h1v.y + a2 * h2v.y + a3 * h3v.y;
                acc[g].z += a0 * h0.z + a1 * h1v.z + a2 * h2v.z + a3 * h3v.z;
                acc[g].w += a0 * h0.w + a1 * h1v.w + a2 * h2v.w + a3 * h3v.w;
            }
        }
    }

    #pragma unroll
    for (int g = 0; g < NQ; ++g) {
        float d = den[g];
        #pragma unroll
        for (int s = 1; s < 64; s <<= 1) d += __shfl_xor(d, s);
        den[g] = d;
    }

    #pragma unroll
    for (int g = 0; g < NQ; ++g) {       // constant-index unroll (rule #20)
        if (g < got) {
            const float inv = 1.0f / den[g];
            float* orow = outb + (size_t)qi[g] * Hh + lane * 4;
            float4 o;
            o.x = acc[g].x * inv; o.y = acc[g].y * inv;
            o.z = acc[g].z * inv; o.w = acc[g].w * inv;
            *(float4*)orow = o;
        }
    }
}

__global__ __launch_bounds__(256) void stattn_fused(
    const float* __restrict__ h_seq,
    const float* __restrict__ tvals,
    float* __restrict__ out)
{
    __shared__ float cts[WB][CAPB];
    __shared__ unsigned short cid[WB][CAPB];
    __shared__ int bcnt[WB];
    __shared__ float tsL[WCAP];
    __shared__ unsigned short idL[WCAP];
    __shared__ int boff[WB + 1];
    __shared__ int ovf_s;

    const int tid  = threadIdx.x;
    const int lane = tid & 63;
    const int wv   = tid >> 6;

    // XCD-contiguous swizzle: 1024 blocks -> 128 contiguous logical per XCD,
    // 2 XCDs per batch so t (16 KB) and the 4 MB h panel stay L2-resident.
    const int phys = blockIdx.x;
    const int lb   = (phys & 7) * 128 + (phys >> 3);
    const int b    = lb >> 8;
    const int m    = lb & 255;
    const int k0   = m * QB;

    const float* tb   = tvals + (size_t)b * Tt;
    const float* hb   = h_seq + (size_t)b * Tt * Hh;
    float*       outb = out   + (size_t)b * Tt * Hh;

    if (tid < WB) bcnt[tid] = 0;
    if (tid == 0) ovf_s = 0;
    __syncthreads();

    // ---- phase 1: scan batch t; direct bucket-slotted staging
    #pragma unroll
    for (int c = 0; c < 4; ++c) {
        const int j4 = c * 1024 + tid * 4;
        const float4 tv = *(const float4*)&tb[j4];
        #pragma unroll
        for (int u = 0; u < 4; ++u) {
            const float ts = (&tv.x)[u] * 4096.0f;
            const int   kk = bucket_of(ts);
            if (kk >= k0 - 3 && kk <= k0 + QB + 2) {   // rare: execz-skipped
                const int wb = kk - (k0 - 3);
                const int s  = atomicAdd(&bcnt[wb], 1);
                if (s < CAPB) {
                    cts[wb][s] = ts;
                    cid[wb][s] = (unsigned short)(j4 + u);
                } else ovf_s = 1;
            }
        }
    }
    __syncthreads();

    // ---- phase 2a: prefix over WB bucket counts (wave 0, shfl scan)
    if (tid < 64) {
        int c = 0;
        if (lane < WB) {
            c = bcnt[lane];
            c = c > CAPB ? CAPB : c;
            bcnt[lane] = c;                  // cap in place
        }
        int x = c;
        #pragma unroll
        for (int d = 1; d < 16; d <<= 1) {
            const int y = __shfl_up(x, d);
            if (lane >= d) x += y;
        }
        if (lane < WB) boff[lane] = x - c;
        if (lane == WB - 1) boff[WB] = x;
    }
    __syncthreads();

    // ---- phase 2b: compact slots into bucket-ordered contiguous list
    for (int i = tid; i < WCAP; i += 256) {
        const int wb = i >> 5;              // CAPB = 32
        const int s  = i & (CAPB - 1);
        if (s < bcnt[wb]) {
            const int sl = boff[wb] + s;
            tsL[sl] = cts[wb][s];
            idL[sl] = cid[wb][s];
        }
    }
    __syncthreads();

    if (ovf_s) {
        // exact dense fallback (never triggers for this input; keeps the
        // kernel correct for any input). Wave wv: queries j % 4 == wv.
        for (int j = wv; j < Tt; j += 4) {
            const float tsq = tb[j] * 4096.0f;
            const int   kk  = bucket_of(tsq);
            if (kk < k0 || kk >= k0 + QB) continue;
            float4 acc = make_float4(0.f,0.f,0.f,0.f);
            float  den = 0.f;
            for (int key = 0; key < Tt; ++key) {
                const float x = tsq - tb[key] * 4096.0f;
                const float w = __expf(-x * x);
                den += w;
                if (w > 0.f) {
                    const float4 hv = *(const float4*)&hb[(size_t)key * Hh + lane * 4];
                    acc.x += w * hv.x; acc.y += w * hv.y;
                    acc.z += w * hv.z; acc.w += w * hv.w;
                }
            }
            const float inv = 1.0f / den;
            float4 o;
            o.x = acc.x * inv; o.y = acc.y * inv;
            o.z = acc.z * inv; o.w = acc.w * inv;
            *(float4*)&outb[(size_t)j * Hh + lane * 4] = o;
        }
        return;
    }

    // ---- phase 3: wave wv owns bucket k0+wv = window bucket 3+wv.
    // Its queries are that bucket's compacted slots; its candidates are the
    // 7-bucket sub-window [wv, wv+7) (everything else has w == 0 exactly).
    const int qlo = boff[3 + wv];
    const int nq  = boff[4 + wv] - qlo;
    const int lo  = boff[wv];
    const int hi  = boff[wv + 7];

    for (int qs = 0; qs < nq; qs += 8) {
        const int got = (nq - qs) > 8 ? 8 : (nq - qs);

        float tq[8]; int qi[8];
        #pragma unroll
        for (int g = 0; g < 8; ++g) {        // constant-index reads (rule #20)
            if (g < got) { tq[g] = tsL[qlo + qs + g]; qi[g] = (int)idL[qlo + qs + g]; }
            else         { tq[g] = -3.0e18f;          qi[g] = 0; }
        }

        if (got <= 4) process_pass<4>(tsL, idL, lo, hi, tq, qi, got, lane, hb, outb);
        else          process_pass<8>(tsL, idL, lo, hi, tq, qi, got, lane, hb, outb);
    }
}

extern "C" void kernel_launch(void* const* d_in, const int* in_sizes, int n_in,
                              void* d_out, int out_size, void* d_ws, size_t ws_size,
                              hipStream_t stream) {
    const float* h_seq = (const float*)d_in[0];
    const float* tvals = (const float*)d_in[1];
    float* out = (float*)d_out;
    // grid = B * (NBK / QB) = 4 * 256 = 1024 blocks, 256 threads (4 waves)
    stattn_fused<<<dim3(Bb * (NBK / QB)), dim3(256), 0, stream>>>(h_seq, tvals, out);
    (void)d_ws; (void)ws_size; (void)in_sizes; (void)n_in; (void)out_size;
}